// Round 10
// baseline (188.686 us; speedup 1.0000x reference)
//
#include <hip/hip_runtime.h>

typedef _Float16 f16;
typedef _Float16 f16x2 __attribute__((ext_vector_type(2)));
typedef _Float16 f16x4 __attribute__((ext_vector_type(4)));
typedef _Float16 f16x8 __attribute__((ext_vector_type(8)));
typedef float    f32x4 __attribute__((ext_vector_type(4)));
typedef unsigned int u32;

#define LOG2E 1.44269504088896340736f

__device__ __forceinline__ f16x2 habs2(f16x2 v) {
    union { f16x2 h; u32 u; } x; x.h = v; x.u &= 0x7FFF7FFFu; return x.h;
}
#if __has_builtin(__builtin_amdgcn_fdot2)
__device__ __forceinline__ float fdot2f(f16x2 a, f16x2 b, float c) {
    return __builtin_amdgcn_fdot2(a, b, c, false);
}
#else
__device__ __forceinline__ float fdot2f(f16x2 a, f16x2 b, float c) {
    return c + (float)a.x * (float)b.x + (float)a.y * (float)b.y;
}
#endif
#if __has_builtin(__builtin_amdgcn_exp2f)
#define EXP2F __builtin_amdgcn_exp2f
#else
#define EXP2F exp2f
#endif

// ---------------------------------------------------------------------------
// K1: projections directly from f32 W (coalesced across col), f32 accumulate,
// f16 store. grid 256 x 384; block = 4 nodes; t>>7 selects W, t&127 = column.
//   Wlh f16 [j][128]; WrL f16 [4h][8c][1024j][4l]; VL f16 [4h][32d][1024j]
// ---------------------------------------------------------------------------
__global__ __launch_bounds__(384) void k1_proj(
        const float* __restrict__ h,  const float* __restrict__ Wl,
        const float* __restrict__ Wr, const float* __restrict__ Wv,
        f16* __restrict__ Wlh, f16* __restrict__ WrL, f16* __restrict__ VL) {
    __shared__ float hs[4][128];
    const int t = threadIdx.x, i0 = blockIdx.x * 4;
    for (int idx = t; idx < 512; idx += 384)
        hs[idx >> 7][idx & 127] = h[(i0 + (idx >> 7)) * 128 + (idx & 127)];
    __syncthreads();

    const int wsel = t >> 7, col = t & 127;
    const float* W = (wsel == 0) ? Wl : ((wsel == 1) ? Wr : Wv);
    float a0 = 0.f, a1 = 0.f, a2 = 0.f, a3 = 0.f;
    #pragma unroll 8
    for (int k = 0; k < 128; k++) {
        float wv = W[k * 128 + col];
        a0 += hs[0][k] * wv; a1 += hs[1][k] * wv;
        a2 += hs[2][k] * wv; a3 += hs[3][k] * wv;
    }
    float accs[4] = {a0, a1, a2, a3};
    const int hh = col >> 5, dd = col & 31, c = dd >> 2, l = dd & 3;
    #pragma unroll
    for (int i = 0; i < 4; i++) {
        int j = i0 + i;
        f16 hv = (f16)accs[i];
        if (wsel == 0)      Wlh[j * 128 + col] = hv;
        else if (wsel == 1) WrL[((hh * 8 + c) * 1024 + j) * 4 + l] = hv;
        else                VL[(hh * 32 + dd) * 1024 + j] = hv;
    }
}

// ---------------------------------------------------------------------------
// K2: fused GATv2. grid 512 x 512 — block = 2 nodes, 8 waves
// (wave w -> head hh=w&3, j-half=w>>2), 2 blocks/CU so co-resident blocks
// interleave across each other's barrier drains. LDS ~19 KB.
// lrelu identity: a.lrelu(t) = (0.6a).t + (0.4a).|t|.
// NOTE: launched 4x this round (idempotent) to expose K2's solo duration.
// ---------------------------------------------------------------------------
__global__ __launch_bounds__(512) void GATv2Layer_84447646974220_kernel(
        const f16* __restrict__ Wlh, const f16* __restrict__ WrL,
        const f16* __restrict__ VL,  const int* __restrict__ adj,
        const float* __restrict__ a_, const float* __restrict__ ln_g,
        const float* __restrict__ ln_b, float* __restrict__ out) {

    __shared__ __align__(16) f16 ep[4][2][1024];   // [head][row][j] 16384 B
    __shared__ float aggS[2][2][128];              // [half][row][col] 2048 B
    __shared__ float redM[2][4][2];                // [half][head][row]
    __shared__ float redS[2][4][2];

    const int t    = threadIdx.x;
    const int w    = t >> 6;        // 0..7
    const int lane = t & 63;
    const int hh   = w & 3;         // head
    const int half = w >> 2;        // j-half (0: j<512, 1: j>=512)
    const int i0   = blockIdx.x * 2;

    // per-wave constants: p2 = 0.6*a, q2 = 0.4*a (f16 pairs), Wl head-slices
    f16x2 p2[16], q2[16];
    #pragma unroll
    for (int d2 = 0; d2 < 16; d2++) {
        float a0 = a_[2 * d2], a1 = a_[2 * d2 + 1];
        f16x2 p; p.x = (f16)(0.6f * a0); p.y = (f16)(0.6f * a1);
        f16x2 q; q.x = (f16)(0.4f * a0); q.y = (f16)(0.4f * a1);
        p2[d2] = p; q2[d2] = q;
    }
    f16x2 wl2[2][16];
    #pragma unroll
    for (int ii = 0; ii < 2; ii++) {
        const f16x2* src = (const f16x2*)(Wlh + (i0 + ii) * 128 + hh * 32);
        #pragma unroll
        for (int c2 = 0; c2 < 16; c2++) wl2[ii][c2] = src[c2];
    }

    // ---- phase 1: scores e[i][j] for this wave's (head, half) ----
    float maxE[2] = {-__builtin_inff(), -__builtin_inff()};

    #pragma unroll 1
    for (int jb = 0; jb < 8; jb++) {
        int j = half * 512 + jb * 64 + lane;
        f16x4 wr[8];
        #pragma unroll
        for (int c = 0; c < 8; c++)
            wr[c] = *(const f16x4*)(WrL + ((hh * 8 + c) * 1024 + j) * 4);
        int am[2];
        #pragma unroll
        for (int ii = 0; ii < 2; ii++) am[ii] = adj[(i0 + ii) * 1024 + j];

        float e[2] = {0.f, 0.f};
        #pragma unroll
        for (int c = 0; c < 8; c++) {
            #pragma unroll
            for (int ii = 0; ii < 2; ii++) {
                f16x2 t0 = wl2[ii][2 * c]     + wr[c].lo;
                f16x2 t1 = wl2[ii][2 * c + 1] + wr[c].hi;
                e[ii] = fdot2f(p2[2 * c],     t0, e[ii]);
                e[ii] = fdot2f(q2[2 * c],     habs2(t0), e[ii]);
                e[ii] = fdot2f(p2[2 * c + 1], t1, e[ii]);
                e[ii] = fdot2f(q2[2 * c + 1], habs2(t1), e[ii]);
            }
        }
        #pragma unroll
        for (int ii = 0; ii < 2; ii++) {
            float v = am[ii] ? e[ii] : -__builtin_inff();
            maxE[ii] = fmaxf(maxE[ii], v);
            ep[hh][ii][j] = (f16)v;
        }
    }

    // ---- phase 2: softmax (cross-half max/sum through LDS) ----
    #pragma unroll
    for (int ii = 0; ii < 2; ii++) {
        float M = maxE[ii];
        #pragma unroll
        for (int off = 32; off > 0; off >>= 1) M = fmaxf(M, __shfl_xor(M, off));
        if (lane == 0) redM[half][hh][ii] = M;
    }
    __syncthreads();

    #pragma unroll
    for (int ii = 0; ii < 2; ii++) {
        float M = fmaxf(redM[0][hh][ii], redM[1][hh][ii]);
        f16x8 v0 = *(f16x8*)&ep[hh][ii][half * 512 + lane * 8];
        float pb[8], l = 0.f;
        #pragma unroll
        for (int e = 0; e < 8; e++) pb[e] = EXP2F(((float)v0[e] - M) * LOG2E);
        #pragma unroll
        for (int e = 0; e < 8; e++) { v0[e] = (f16)pb[e]; l += pb[e]; }
        *(f16x8*)&ep[hh][ii][half * 512 + lane * 8] = v0;
        #pragma unroll
        for (int off = 32; off > 0; off >>= 1) l += __shfl_xor(l, off);
        if (lane == 0) redS[half][hh][ii] = l;
    }
    __syncthreads();

    float lr[2];
    #pragma unroll
    for (int ii = 0; ii < 2; ii++)
        lr[ii] = 1.0f / (redS[0][hh][ii] + redS[1][hh][ii]);

    // ---- phase 3: agg = p @ V via MFMA (this wave's 512-j slice) ----
    // A rows m: ep[hh][m&1] -> C rows 0,1 are nodes 0,1 (rest discarded).
    // B from VL[d=n][j=k] contiguous. C/D: col=lane&15, row=(lane>>4)*4+reg.
    f32x4 acc0 = {0.f, 0.f, 0.f, 0.f}, acc1 = {0.f, 0.f, 0.f, 0.f};
    const int q8  = (lane >> 4) << 3;
    const int m1  = lane & 1;
    const int n15 = lane & 15;

    #pragma unroll 1
    for (int jt4 = 0; jt4 < 4; jt4++) {
        int jt = half * 4 + jt4;
        #pragma unroll
        for (int kk = 0; kk < 4; kk++) {
            int ko = jt * 128 + kk * 32 + q8;
            f16x8 af = *(const f16x8*)&ep[hh][m1][ko];
            f16x8 b0 = *(const f16x8*)(VL + (hh * 32 + n15) * 1024 + ko);
            f16x8 b1 = *(const f16x8*)(VL + (hh * 32 + 16 + n15) * 1024 + ko);
            acc0 = __builtin_amdgcn_mfma_f32_16x16x32_f16(af, b0, acc0, 0, 0, 0);
            acc1 = __builtin_amdgcn_mfma_f32_16x16x32_f16(af, b1, acc1, 0, 0, 0);
        }
    }

    if (lane < 16) {
        #pragma unroll
        for (int r = 0; r < 2; r++) {
            aggS[half][r][hh * 32 + lane]      = acc0[r] * lr[r];
            aggS[half][r][hh * 32 + 16 + lane] = acc1[r] * lr[r];
        }
    }
    __syncthreads();

    // ---- phase 4: LayerNorm + ReLU (waves 0..1, one node each) ----
    if (w < 2) {
        float x0 = aggS[0][w][lane]      + aggS[1][w][lane];
        float x1 = aggS[0][w][lane + 64] + aggS[1][w][lane + 64];
        float s = x0 + x1, sq = x0 * x0 + x1 * x1;
        #pragma unroll
        for (int off = 32; off > 0; off >>= 1) {
            s  += __shfl_xor(s, off);
            sq += __shfl_xor(sq, off);
        }
        float mean = s * (1.f / 128.f);
        float var  = sq * (1.f / 128.f) - mean * mean;
        float rs   = rsqrtf(var + 1e-5f);
        float y0 = fmaxf((x0 - mean) * rs * ln_g[lane]      + ln_b[lane],      0.f);
        float y1 = fmaxf((x1 - mean) * rs * ln_g[lane + 64] + ln_b[lane + 64], 0.f);
        out[(i0 + w) * 128 + lane]      = y0;
        out[(i0 + w) * 128 + 64 + lane] = y1;
    }
}

// ---------------------------------------------------------------------------
extern "C" void kernel_launch(void* const* d_in, const int* in_sizes, int n_in,
                              void* d_out, int out_size, void* d_ws, size_t ws_size,
                              hipStream_t stream) {
    const float* h   = (const float*)d_in[0];
    const int*   adj = (const int*)d_in[1];
    const float* Wl  = (const float*)d_in[2];
    const float* Wr  = (const float*)d_in[3];
    const float* Wv  = (const float*)d_in[4];
    const float* a_  = (const float*)d_in[5];
    const float* g_  = (const float*)d_in[6];
    const float* b_  = (const float*)d_in[7];
    float* out = (float*)d_out;

    char* ws = (char*)d_ws;
    f16* Wlh = (f16*)(ws);                 // 1024*128 f16    = 262144 B
    f16* WrL = (f16*)(ws + 262144);        // [4][8][1024][4] = 262144 B
    f16* VL  = (f16*)(ws + 524288);        // [4][32][1024]   = 262144 B

    k1_proj<<<256, 384, 0, stream>>>(h, Wl, Wr, Wv, Wlh, WrL, VL);
    // K2 launched 4x (idempotent) this round to expose its solo duration in
    // the dur delta / profiler top-5. Revert to 1x next round.
    for (int rep = 0; rep < 4; rep++)
        GATv2Layer_84447646974220_kernel<<<512, 512, 0, stream>>>(
            Wlh, WrL, VL, adj, a_, g_, b_, out);
}

// Round 11
// 102.290 us; speedup vs baseline: 1.8446x; 1.8446x over previous
//
#include <hip/hip_runtime.h>

typedef _Float16 f16;
typedef _Float16 f16x2 __attribute__((ext_vector_type(2)));
typedef _Float16 f16x4 __attribute__((ext_vector_type(4)));
typedef _Float16 f16x8 __attribute__((ext_vector_type(8)));
typedef float    f32x4 __attribute__((ext_vector_type(4)));
typedef unsigned int u32;

#define LOG2E 1.44269504088896340736f

__device__ __forceinline__ f16x2 habs2(f16x2 v) {
    union { f16x2 h; u32 u; } x; x.h = v; x.u &= 0x7FFF7FFFu; return x.h;
}
#if __has_builtin(__builtin_amdgcn_fdot2)
__device__ __forceinline__ float fdot2f(f16x2 a, f16x2 b, float c) {
    return __builtin_amdgcn_fdot2(a, b, c, false);
}
#else
__device__ __forceinline__ float fdot2f(f16x2 a, f16x2 b, float c) {
    return c + (float)a.x * (float)b.x + (float)a.y * (float)b.y;
}
#endif
#if __has_builtin(__builtin_amdgcn_exp2f)
#define EXP2F __builtin_amdgcn_exp2f
#else
#define EXP2F exp2f
#endif

// ---------------------------------------------------------------------------
// K1: projections from f32 W (coalesced across col), f32 accumulate, f16
// store. grid 512 x 384; block = 2 nodes (2 blk/CU, 3 waves/SIMD); unroll 16
// keeps 16 W-loads in flight. t>>7 selects W_l/W_r/W_v, t&127 = column.
//   Wlh f16 [j][128]; WrL f16 [4h][8c][1024j][4l]; VL f16 [4h][32d][1024j]
// ---------------------------------------------------------------------------
__global__ __launch_bounds__(384) void k1_proj(
        const float* __restrict__ h,  const float* __restrict__ Wl,
        const float* __restrict__ Wr, const float* __restrict__ Wv,
        f16* __restrict__ Wlh, f16* __restrict__ WrL, f16* __restrict__ VL) {
    __shared__ float hs[2][128];
    const int t = threadIdx.x, i0 = blockIdx.x * 2;
    if (t < 256) hs[t >> 7][t & 127] = h[(i0 + (t >> 7)) * 128 + (t & 127)];
    __syncthreads();

    const int wsel = t >> 7, col = t & 127;
    const float* W = (wsel == 0) ? Wl : ((wsel == 1) ? Wr : Wv);
    float a0 = 0.f, a1 = 0.f;
    #pragma unroll 16
    for (int k = 0; k < 128; k++) {
        float wv = W[k * 128 + col];
        a0 += hs[0][k] * wv;
        a1 += hs[1][k] * wv;
    }
    float accs[2] = {a0, a1};
    const int hh = col >> 5, dd = col & 31, c = dd >> 2, l = dd & 3;
    #pragma unroll
    for (int i = 0; i < 2; i++) {
        int j = i0 + i;
        f16 hv = (f16)accs[i];
        if (wsel == 0)      Wlh[j * 128 + col] = hv;
        else if (wsel == 1) WrL[((hh * 8 + c) * 1024 + j) * 4 + l] = hv;
        else                VL[(hh * 32 + dd) * 1024 + j] = hv;
    }
}

// ---------------------------------------------------------------------------
// K2: fused GATv2, barrier-free waves. grid 512 x 256 — block = 2 nodes,
// 4 waves, wave = head (owns BOTH nodes, FULL j range -> wave-local softmax,
// single __syncthreads before LayerNorm). Phase 1: manual register
// double-buffer on WrL/adj. Phase 3: B-frag prefetch one chunk ahead.
// lrelu identity: a.lrelu(t) = (0.6a).t + (0.4a).|t|.
// ---------------------------------------------------------------------------
__global__ __launch_bounds__(256) void GATv2Layer_84447646974220_kernel(
        const f16* __restrict__ Wlh, const f16* __restrict__ WrL,
        const f16* __restrict__ VL,  const int* __restrict__ adj,
        const float* __restrict__ a_, const float* __restrict__ ln_g,
        const float* __restrict__ ln_b, float* __restrict__ out) {

    __shared__ __align__(16) f16 ep[4][2][1024];   // [head][node][j] 16384 B
    __shared__ float aggS[2][4][32];               // [node][head][d]  1024 B

    const int t    = threadIdx.x;
    const int lane = t & 63;
    const int hh   = t >> 6;        // wave = head
    const int i0   = blockIdx.x * 2;

    // per-wave constants: p2 = 0.6*a, q2 = 0.4*a (f16 pairs), Wl head-slices
    f16x2 p2[16], q2[16];
    #pragma unroll
    for (int d2 = 0; d2 < 16; d2++) {
        float a0 = a_[2 * d2], a1 = a_[2 * d2 + 1];
        f16x2 p; p.x = (f16)(0.6f * a0); p.y = (f16)(0.6f * a1);
        f16x2 q; q.x = (f16)(0.4f * a0); q.y = (f16)(0.4f * a1);
        p2[d2] = p; q2[d2] = q;
    }
    f16x2 wl2[2][16];
    #pragma unroll
    for (int ii = 0; ii < 2; ii++) {
        const f16x2* src = (const f16x2*)(Wlh + (i0 + ii) * 128 + hh * 32);
        #pragma unroll
        for (int c2 = 0; c2 < 16; c2++) wl2[ii][c2] = src[c2];
    }

    // ---- phase 1: scores, 16 chunks of 64 j, double-buffered loads ----
    float maxE[2] = {-__builtin_inff(), -__builtin_inff()};
    f16x4 wrA[8], wrB[8];
    int   amA[2], amB[2];

    #pragma unroll
    for (int c = 0; c < 8; c++)
        wrA[c] = *(const f16x4*)(WrL + ((hh * 8 + c) * 1024 + lane) * 4);
    amA[0] = adj[(i0 + 0) * 1024 + lane];
    amA[1] = adj[(i0 + 1) * 1024 + lane];

    #pragma unroll
    for (int jb = 0; jb < 16; jb++) {
        const bool even = (jb & 1) == 0;
        f16x4* cur = even ? wrA : wrB;
        int*   amc = even ? amA : amB;
        f16x4* nxt = even ? wrB : wrA;
        int*   amn = even ? amB : amA;
        if (jb < 15) {                       // issue next chunk's loads first
            int jn = (jb + 1) * 64 + lane;
            #pragma unroll
            for (int c = 0; c < 8; c++)
                nxt[c] = *(const f16x4*)(WrL + ((hh * 8 + c) * 1024 + jn) * 4);
            amn[0] = adj[(i0 + 0) * 1024 + jn];
            amn[1] = adj[(i0 + 1) * 1024 + jn];
        }
        int j = jb * 64 + lane;
        float e[2] = {0.f, 0.f};
        #pragma unroll
        for (int c = 0; c < 8; c++) {
            #pragma unroll
            for (int ii = 0; ii < 2; ii++) {
                f16x2 t0 = wl2[ii][2 * c]     + cur[c].lo;
                f16x2 t1 = wl2[ii][2 * c + 1] + cur[c].hi;
                e[ii] = fdot2f(p2[2 * c],     t0, e[ii]);
                e[ii] = fdot2f(q2[2 * c],     habs2(t0), e[ii]);
                e[ii] = fdot2f(p2[2 * c + 1], t1, e[ii]);
                e[ii] = fdot2f(q2[2 * c + 1], habs2(t1), e[ii]);
            }
        }
        #pragma unroll
        for (int ii = 0; ii < 2; ii++) {
            float v = amc[ii] ? e[ii] : -__builtin_inff();
            maxE[ii] = fmaxf(maxE[ii], v);
            ep[hh][ii][j] = (f16)v;
        }
    }

    // ---- phase 2: wave-local softmax (wave owns full j for both nodes) ----
    float lr[2];
    #pragma unroll
    for (int ii = 0; ii < 2; ii++) {
        float M = maxE[ii];
        #pragma unroll
        for (int off = 32; off > 0; off >>= 1) M = fmaxf(M, __shfl_xor(M, off));
        float l = 0.f;
        #pragma unroll
        for (int g = 0; g < 2; g++) {
            f16x8 v = *(f16x8*)&ep[hh][ii][lane * 16 + g * 8];
            float pb[8];
            #pragma unroll
            for (int e = 0; e < 8; e++) pb[e] = EXP2F(((float)v[e] - M) * LOG2E);
            #pragma unroll
            for (int e = 0; e < 8; e++) { v[e] = (f16)pb[e]; l += pb[e]; }
            *(f16x8*)&ep[hh][ii][lane * 16 + g * 8] = v;
        }
        #pragma unroll
        for (int off = 32; off > 0; off >>= 1) l += __shfl_xor(l, off);
        lr[ii] = 1.0f / l;
    }

    // ---- phase 3: agg = p @ V via MFMA, 32 chunks, B-frag prefetch ----
    // A rows alternate node0/node1 (m parity); C rows 0,1 = nodes 0,1.
    // B from VL[d=n][j=k] contiguous. C/D: col=lane&15, row=(lane>>4)*4+reg.
    f32x4 acc0 = {0.f, 0.f, 0.f, 0.f}, acc1 = {0.f, 0.f, 0.f, 0.f};
    const int q8  = (lane >> 4) << 3;
    const int m1  = lane & 1;
    const int n15 = lane & 15;
    const f16* vb = VL + (hh * 32 + n15) * 1024;

    f16x8 b0C = *(const f16x8*)(vb + q8);
    f16x8 b1C = *(const f16x8*)(vb + 16384 + q8);
    #pragma unroll
    for (int s = 0; s < 32; s++) {
        int ko = s * 32 + q8;
        f16x8 af = *(const f16x8*)&ep[hh][m1][ko];
        if (s < 31) {
            int koN = ko + 32;
            f16x8 b0N = *(const f16x8*)(vb + koN);
            f16x8 b1N = *(const f16x8*)(vb + 16384 + koN);
            acc0 = __builtin_amdgcn_mfma_f32_16x16x32_f16(af, b0C, acc0, 0, 0, 0);
            acc1 = __builtin_amdgcn_mfma_f32_16x16x32_f16(af, b1C, acc1, 0, 0, 0);
            b0C = b0N; b1C = b1N;
        } else {
            acc0 = __builtin_amdgcn_mfma_f32_16x16x32_f16(af, b0C, acc0, 0, 0, 0);
            acc1 = __builtin_amdgcn_mfma_f32_16x16x32_f16(af, b1C, acc1, 0, 0, 0);
        }
    }

    if (lane < 16) {
        aggS[0][hh][lane]      = acc0[0] * lr[0];
        aggS[0][hh][16 + lane] = acc1[0] * lr[0];
        aggS[1][hh][lane]      = acc0[1] * lr[1];
        aggS[1][hh][16 + lane] = acc1[1] * lr[1];
    }
    __syncthreads();   // the only block-wide barrier

    // ---- phase 4: LayerNorm + ReLU (wave 0 -> node 0, wave 1 -> node 1) ----
    if (t < 128) {
        const int node = t >> 6, ln2 = t & 63;
        float x0 = aggS[node][ln2 >> 5][ln2 & 31];          // col = ln2
        float x1 = aggS[node][2 + (ln2 >> 5)][ln2 & 31];    // col = ln2+64
        float s = x0 + x1, sq = x0 * x0 + x1 * x1;
        #pragma unroll
        for (int off = 32; off > 0; off >>= 1) {
            s  += __shfl_xor(s, off);
            sq += __shfl_xor(sq, off);
        }
        float mean = s * (1.f / 128.f);
        float var  = sq * (1.f / 128.f) - mean * mean;
        float rs   = rsqrtf(var + 1e-5f);
        float y0 = fmaxf((x0 - mean) * rs * ln_g[ln2]      + ln_b[ln2],      0.f);
        float y1 = fmaxf((x1 - mean) * rs * ln_g[ln2 + 64] + ln_b[ln2 + 64], 0.f);
        out[(i0 + node) * 128 + ln2]      = y0;
        out[(i0 + node) * 128 + 64 + ln2] = y1;
    }
}

// ---------------------------------------------------------------------------
extern "C" void kernel_launch(void* const* d_in, const int* in_sizes, int n_in,
                              void* d_out, int out_size, void* d_ws, size_t ws_size,
                              hipStream_t stream) {
    const float* h   = (const float*)d_in[0];
    const int*   adj = (const int*)d_in[1];
    const float* Wl  = (const float*)d_in[2];
    const float* Wr  = (const float*)d_in[3];
    const float* Wv  = (const float*)d_in[4];
    const float* a_  = (const float*)d_in[5];
    const float* g_  = (const float*)d_in[6];
    const float* b_  = (const float*)d_in[7];
    float* out = (float*)d_out;

    char* ws = (char*)d_ws;
    f16* Wlh = (f16*)(ws);                 // 1024*128 f16    = 262144 B
    f16* WrL = (f16*)(ws + 262144);        // [4][8][1024][4] = 262144 B
    f16* VL  = (f16*)(ws + 524288);        // [4][32][1024]   = 262144 B

    k1_proj<<<512, 384, 0, stream>>>(h, Wl, Wr, Wv, Wlh, WrL, VL);
    GATv2Layer_84447646974220_kernel<<<512, 256, 0, stream>>>(
        Wlh, WrL, VL, adj, a_, g_, b_, out);
}